// Round 6
// baseline (140.931 us; speedup 1.0000x reference)
//
#include <hip/hip_runtime.h>

typedef unsigned short ushort_t;
typedef __attribute__((ext_vector_type(8))) short short8;   // 8 bf16 payload (4 VGPRs)
typedef __attribute__((ext_vector_type(4))) float floatx4;  // MFMA C/D + epi math
typedef __attribute__((ext_vector_type(2))) float floatx2;

#define NN    32
#define CIN   128
#define COUT  256
#define NPTS  16384            // bs*v = 4*4096
#define NSAMP (NPTS * NN)      // 524288
#define LDA   136              // LDS A-tile stride (+16B pad)
#define HB    128              // histogram partial blocks (32 per batch)

// All scratch in .so-resident device globals. NO atomics anywhere -> every
// buffer is fully overwritten each run -> no zeroing kernel, no cross-run state.
__device__ __align__(16) ushort_t g_wb[COUT * CIN];            // 64 KB: W as bf16
__device__ __align__(16) ushort_t g_y[(size_t)NPTS * COUT];    // 8 MB: Y = fsp * W^T, bf16
__device__ __align__(16) int      g_hp[HB * 4096];             // 2 MB: per-chunk histograms
__device__ __align__(16) float    g_sp[256 * 512];             // 512 KB: per-block BN partials
__device__ __align__(16) float    g_consts[1536];              // scale,shift,d0,s0,s1,s2 per ch

__device__ __forceinline__ float bf2f(ushort_t u) {
    return __uint_as_float(((unsigned int)u) << 16);
}
__device__ __forceinline__ ushort_t f2bf(float f) {
    unsigned int x = __float_as_uint(f);
    return (ushort_t)((x + 0x7FFFu + ((x >> 16) & 1u)) >> 16);  // RNE
}
// Per-wave dtype probe: bf16 verts look plausible as bf16; f32 low halves don't.
__device__ __forceinline__ int probe_f32(const void* verts, int lane) {
    float ax = fabsf(bf2f(((const ushort_t*)verts)[lane]));
    unsigned long long b = __ballot((ax > 1e-5f) && (ax < 32.0f));
    return (__popcll(b) >= 56) ? 0 : 1;
}
__device__ __forceinline__ float bperm_f(int abytes, float v) {
    return __uint_as_float((unsigned)__builtin_amdgcn_ds_bpermute(abytes, __float_as_int(v)));
}

// ---------------------------------------------------------------------------
// Kernel 1: atomic-free neighbor histogram partials + W -> bf16.
// Blocks [0,128): block b owns samples [b*4096,(b+1)*4096) -- all in batch
// b>>5 -- LDS-histograms them over the batch's 4096 vertices, stores partials.
// Blocks [128,160): convert W (32768 elems).
// ---------------------------------------------------------------------------
__global__ __launch_bounds__(256)
void hist_kernel(const int* __restrict__ nbr,
                 const void* __restrict__ Wg,
                 const void* __restrict__ verts) {
    __shared__ int h[4096];
    const int b   = blockIdx.x;
    const int tid = threadIdx.x;
    if (b < HB) {
        #pragma unroll
        for (int i = 0; i < 16; ++i) h[i * 256 + tid] = 0;
        __syncthreads();
        const int* src = nbr + (size_t)b * 4096;
        #pragma unroll
        for (int i = 0; i < 16; ++i) atomicAdd(&h[src[i * 256 + tid]], 1);  // LDS atomics only
        __syncthreads();
        int* dst = g_hp + (size_t)b * 4096;
        #pragma unroll
        for (int i = 0; i < 16; ++i) dst[i * 256 + tid] = h[i * 256 + tid];
    } else {
        const int f32 = probe_f32(verts, tid & 63);
        int i = (b - HB) * 1024 + tid * 4;
        if (f32) {
            float4 v = ((const float4*)Wg)[i >> 2];
            g_wb[i] = f2bf(v.x); g_wb[i + 1] = f2bf(v.y);
            g_wb[i + 2] = f2bf(v.z); g_wb[i + 3] = f2bf(v.w);
        } else {
            *(uint2*)(g_wb + i) = *(const uint2*)((const ushort_t*)Wg + i);
        }
    }
}

// ---------------------------------------------------------------------------
// Kernel 2: fused fsp-build + Y-GEMM + BN partial stats (no atomics).
// Stages 64 rows of [bf16(feat 0..126) ++ bf16(||row||)] straight from
// feature_map into LDS, then M=64 x N=256 x K=128 MFMA GEMM; epilogue stores
// Y bf16 + per-block mult-weighted sum/sumsq partials to g_sp[block].
// ---------------------------------------------------------------------------
__global__ __launch_bounds__(256, 2)
void ygemm_kernel(const void* __restrict__ fm, const void* __restrict__ verts) {
    __shared__ __align__(16) ushort_t At[64 * LDA];
    __shared__ float multS[64];

    const int tid  = threadIdx.x;
    const int r0   = blockIdx.x * 64;
    const int lane = tid & 63;
    const int f32  = probe_f32(verts, lane);

    if (tid < 64) {   // multiplicity = sum of the batch's 32 histogram partials
        const int* hp = g_hp + (size_t)(r0 >> 12) * 32 * 4096 + (r0 & 4095) + tid;
        int s = 0;
        #pragma unroll
        for (int p2 = 0; p2 < 32; ++p2) s += hp[(size_t)p2 * 4096];
        multS[tid] = (float)s;
    }

    const int rl4 = tid >> 6;
    #pragma unroll 4
    for (int i = 0; i < 16; ++i) {
        const int rl = i * 4 + rl4;
        float f0, f1; ushort_t u0, u1;
        if (f32) {
            const float* src = (const float*)fm + (size_t)(r0 + rl) * 127;
            f0 = src[lane];
            f1 = (lane < 63) ? src[64 + lane] : 0.0f;
            u0 = f2bf(f0); u1 = f2bf(f1);
        } else {
            const ushort_t* src = (const ushort_t*)fm + (size_t)(r0 + rl) * 127;
            u0 = src[lane];
            u1 = (lane < 63) ? src[64 + lane] : (ushort_t)0;
            f0 = bf2f(u0); f1 = bf2f(u1);
        }
        float ss = f0 * f0 + f1 * f1;                 // fdist in fp32 (matches ref)
        #pragma unroll
        for (int d = 1; d < 64; d <<= 1) ss += __shfl_xor(ss, d, 64);
        At[rl * LDA + lane]      = u0;
        At[rl * LDA + 64 + lane] = (lane < 63) ? u1 : f2bf(sqrtf(ss));
    }
    __syncthreads();

    const int w = tid >> 6;              // wave -> channel strip w*64
    const int m = lane & 15;
    const int q = lane >> 4;

    floatx4 acc[4][4];
    #pragma unroll
    for (int rt = 0; rt < 4; ++rt)
        #pragma unroll
        for (int ct = 0; ct < 4; ++ct)
            acc[rt][ct] = (floatx4){0.0f, 0.0f, 0.0f, 0.0f};

    #pragma unroll
    for (int kk = 0; kk < 4; ++kk) {
        const int kof = kk * 32 + q * 8;
        short8 af[4];
        #pragma unroll
        for (int rt = 0; rt < 4; ++rt)
            af[rt] = *(const short8*)&At[(rt * 16 + m) * LDA + kof];
        short8 bfr[4];
        #pragma unroll
        for (int ct = 0; ct < 4; ++ct) {
            int ch = w * 64 + ct * 16 + m;
            bfr[ct] = *(const short8*)(g_wb + ch * CIN + kof);  // B[k][n]=W[n][k]
        }
        #pragma unroll
        for (int rt = 0; rt < 4; ++rt)
            #pragma unroll
            for (int ct = 0; ct < 4; ++ct)
                acc[rt][ct] = __builtin_amdgcn_mfma_f32_16x16x32_bf16(
                    af[rt], bfr[ct], acc[rt][ct], 0, 0, 0);
    }

    #pragma unroll
    for (int ct = 0; ct < 4; ++ct) {
        const int ch = w * 64 + ct * 16 + m;
        float s = 0.0f, ss = 0.0f;
        #pragma unroll
        for (int rt = 0; rt < 4; ++rt)
            #pragma unroll
            for (int j = 0; j < 4; ++j) {
                int rloc = rt * 16 + q * 4 + j;       // C/D: row=(lane>>4)*4+reg
                ushort_t yb = f2bf(acc[rt][ct][j]);
                g_y[(size_t)(r0 + rloc) * COUT + ch] = yb;
                float yv = bf2f(yb);                  // same value epi will read
                float wm = multS[rloc];
                s  += wm * yv;
                ss += wm * yv * yv;
            }
        s  += __shfl_xor(s, 16, 64);  s  += __shfl_xor(s, 32, 64);
        ss += __shfl_xor(ss, 16, 64); ss += __shfl_xor(ss, 32, 64);
        if (q == 0) {                                 // plain stores, no atomics
            g_sp[(size_t)blockIdx.x * 512 + ch]       = s;
            g_sp[(size_t)blockIdx.x * 512 + 256 + ch] = ss;
        }
    }
}

// ---------------------------------------------------------------------------
// Kernel 3: reduce the 256 BN partials + per-channel constants.
// bias b cancels exactly in train-mode BN (z - mean(z)) -> never read.
// ---------------------------------------------------------------------------
__global__ void finalize_kernel(const void* __restrict__ gamma,
                                const void* __restrict__ beta,
                                const void* __restrict__ dirs,
                                const void* __restrict__ verts) {
    const int c   = threadIdx.x;                      // 256 threads, 1 block
    const int f32 = probe_f32(verts, c & 63);

    float s = 0.0f, ss = 0.0f;
    #pragma unroll 8
    for (int p2 = 0; p2 < 256; ++p2) {
        s  += g_sp[(size_t)p2 * 512 + c];
        ss += g_sp[(size_t)p2 * 512 + 256 + c];
    }
    const float invN = 1.0f / (float)NSAMP;
    float mean = s * invN;
    float var  = fmaxf(ss * invN - mean * mean, 0.0f);  // biased
    float inv  = 1.0f / sqrtf(var + 1e-5f);
    float ga, be, d0, d1, d2, d3;
    if (f32) {
        ga = ((const float*)gamma)[c]; be = ((const float*)beta)[c];
        const float* dd = (const float*)dirs;
        d0 = dd[c]; d1 = dd[256 + c]; d2 = dd[512 + c]; d3 = dd[768 + c];
    } else {
        ga = bf2f(((const ushort_t*)gamma)[c]); be = bf2f(((const ushort_t*)beta)[c]);
        const ushort_t* dd = (const ushort_t*)dirs;
        d0 = bf2f(dd[c]); d1 = bf2f(dd[256 + c]);
        d2 = bf2f(dd[512 + c]); d3 = bf2f(dd[768 + c]);
    }
    float scale = ga * inv;
    g_consts[c]        = scale;
    g_consts[256 + c]  = be - mean * scale;
    g_consts[512 + c]  = d0;                          // directions[0]
    g_consts[768 + c]  = d1 - d0;                     // sup_w rows
    g_consts[1024 + c] = d2 - d0;
    g_consts[1280 + c] = d3 - d0;
}

// ---------------------------------------------------------------------------
// Kernel 4: epilogue, TWO SAMPLES per wave-iteration. One wave per point;
// half-wave h processes sample 2t+h with 8 ch/lane -> one global_load_dwordx4
// per PAIR covers two full 512B g_y rows (halves the load-inst count). All
// broadcasts (row index + 3 direction weights) ride the DS pipe via
// ds_bpermute (co-issues with VALU; replaces 6 readlane VALU ops/pair).
// Addressing: 1 v_lshl_add -> 32-bit voffset + SGPR base. Per pair ~38 VALU
// vs ~54 before (-30%). 4-pair (8-sample) load pipeline. Halves merge with
// 8 shfl_xor(32)+max once per point; lanes<32 store. Barrier-free, LDS-free.
// XCD-chunked: blocks with bid&7==k cover p in [k*2048,(k+1)*2048) ->
// per-XCD gather set = one batch's 2MB g_y slice (< 4MB per-XCD L2).
// ---------------------------------------------------------------------------
__global__ __launch_bounds__(256, 4)
void epi_kernel(const int* __restrict__ nbr,
                const void* __restrict__ verts,
                void* __restrict__ out) {
    const int tid  = threadIdx.x;
    const int lane = tid & 63;
    const int bid  = blockIdx.x;
    const int p0   = (((bid & 7) << 9) | (bid >> 3)) << 2;   // XCD-chunked, 4 pts
    const int p    = p0 + (tid >> 6);                        // wave -> point
    const int f32  = probe_f32(verts, lane);
    const int j    = lane & 31;                              // owned neighbor

    // --- setup: per-lane direction weight + row, held in VGPRs (no LDS).
    // Lanes j and j+32 replicate neighbor j; bpermute only reads lanes 0..31.
    int   gv;                                                // gathered row
    float wx, wy, wz;
    {
        gv = ((p >> 12) << 12) + nbr[(size_t)p * NN + j];
        float sx, sy, sz, nx, ny, nz;
        if (f32) {
            const float* vv = (const float*)verts;
            sx = vv[p * 3]; sy = vv[p * 3 + 1]; sz = vv[p * 3 + 2];
            nx = vv[gv * 3]; ny = vv[gv * 3 + 1]; nz = vv[gv * 3 + 2];
        } else {
            const ushort_t* vv = (const ushort_t*)verts;
            sx = bf2f(vv[p * 3]); sy = bf2f(vv[p * 3 + 1]); sz = bf2f(vv[p * 3 + 2]);
            nx = bf2f(vv[gv * 3]); ny = bf2f(vv[gv * 3 + 1]); nz = bf2f(vv[gv * 3 + 2]);
        }
        float dx = nx - sx, dy = ny - sy, dz = nz - sz;
        float nrm = sqrtf(dx * dx + dy * dy + dz * dz);
        float inv = 1.0f / fmaxf(nrm, 1e-12f);               // F.normalize eps
        wx = (dx * inv + 1.0f) * 0.5f;
        wy = (dy * inv + 1.0f) * 0.5f;
        wz = (dz * inv + 1.0f) * 0.5f;
    }

    const int hsel = (lane >> 5) << 2;        // bpermute byte addr: which half
    const int cofs = (lane & 31) << 4;        // lane's 16B (8 ch) within a row
    const int c8   = (lane & 31) * 8;         // 8 channels per lane

    const floatx4 zero = {0.0f, 0.0f, 0.0f, 0.0f};
    const floatx4 scL = *(const floatx4*)&g_consts[c8];
    const floatx4 scH = *(const floatx4*)&g_consts[c8 + 4];
    const floatx4 shL = *(const floatx4*)&g_consts[256 + c8];
    const floatx4 shH = *(const floatx4*)&g_consts[256 + c8 + 4];
    const floatx4 d0L = *(const floatx4*)&g_consts[512 + c8];
    const floatx4 d0H = *(const floatx4*)&g_consts[512 + c8 + 4];
    const floatx4 s0L = *(const floatx4*)&g_consts[768 + c8];
    const floatx4 s0H = *(const floatx4*)&g_consts[768 + c8 + 4];
    const floatx4 s1L = *(const floatx4*)&g_consts[1024 + c8];
    const floatx4 s1H = *(const floatx4*)&g_consts[1024 + c8 + 4];
    const floatx4 s2L = *(const floatx4*)&g_consts[1280 + c8];
    const floatx4 s2H = *(const floatx4*)&g_consts[1280 + c8 + 4];

    const char* gyb = (const char*)g_y;
    floatx4 aL0 = zero, aH0 = zero, aL1 = zero, aH1 = zero;  // 2 max chains x 8ch
    uint4 u[4]; float bx[4], by[4], bz[4];                   // 4-pair pipeline

    #pragma unroll
    for (int k = 0; k < 4; ++k) {                            // prologue: pairs 0..3
        const int av = k * 8 + hsel;
        int rw = __builtin_amdgcn_ds_bpermute(av, gv);       // DS-pipe broadcasts
        bx[k] = bperm_f(av, wx);
        by[k] = bperm_f(av, wy);
        bz[k] = bperm_f(av, wz);
        u[k] = *(const uint4*)(gyb + (((unsigned)rw << 9) + (unsigned)cofs));
    }
    #pragma unroll
    for (int g = 0; g < 4; ++g) {
        #pragma unroll
        for (int k = 0; k < 4; ++k) {
            const uint4 uk = u[k];                           // waits this load only
            const float wxs = bx[k], wys = by[k], wzs = bz[k];
            if (g < 3) {                                     // prefetch pair +4
                const int av = (g * 4 + k + 4) * 8 + hsel;
                int rw = __builtin_amdgcn_ds_bpermute(av, gv);
                bx[k] = bperm_f(av, wx);
                by[k] = bperm_f(av, wy);
                bz[k] = bperm_f(av, wz);
                u[k] = *(const uint4*)(gyb + (((unsigned)rw << 9) + (unsigned)cofs));
            }
            floatx4 yL, yH;
            yL.x = __uint_as_float(uk.x << 16);
            yL.y = __uint_as_float(uk.x & 0xFFFF0000u);
            yL.z = __uint_as_float(uk.y << 16);
            yL.w = __uint_as_float(uk.y & 0xFFFF0000u);
            yH.x = __uint_as_float(uk.z << 16);
            yH.y = __uint_as_float(uk.z & 0xFFFF0000u);
            yH.z = __uint_as_float(uk.w << 16);
            yH.w = __uint_as_float(uk.w & 0xFFFF0000u);
            floatx4 thL = d0L + s0L * wxs + s1L * wys + s2L * wzs;
            floatx4 thH = d0H + s0H * wxs + s1H * wys + s2H * wzs;
            thL = __builtin_elementwise_max(thL, zero);
            thH = __builtin_elementwise_max(thH, zero);
            floatx4 ztL = (yL * scL + shL) * thL;            // relu(z)*th == max(z*th,0)
            floatx4 ztH = (yH * scH + shH) * thH;
            if (k & 1) {
                aL1 = __builtin_elementwise_max(aL1, ztL);
                aH1 = __builtin_elementwise_max(aH1, ztH);
            } else {
                aL0 = __builtin_elementwise_max(aL0, ztL);
                aH0 = __builtin_elementwise_max(aH0, ztH);
            }
        }
    }
    floatx4 vL = __builtin_elementwise_max(aL0, aL1);        // accs >= 0
    floatx4 vH = __builtin_elementwise_max(aH0, aH1);

    // merge even-sample half with odd-sample half (same channels, lane^32)
    vL.x = fmaxf(vL.x, __shfl_xor(vL.x, 32, 64));
    vL.y = fmaxf(vL.y, __shfl_xor(vL.y, 32, 64));
    vL.z = fmaxf(vL.z, __shfl_xor(vL.z, 32, 64));
    vL.w = fmaxf(vL.w, __shfl_xor(vL.w, 32, 64));
    vH.x = fmaxf(vH.x, __shfl_xor(vH.x, 32, 64));
    vH.y = fmaxf(vH.y, __shfl_xor(vH.y, 32, 64));
    vH.z = fmaxf(vH.z, __shfl_xor(vH.z, 32, 64));
    vH.w = fmaxf(vH.w, __shfl_xor(vH.w, 32, 64));

    if (lane < 32) {
        size_t ofs = (size_t)p * COUT + c8;
        if (f32) {
            *(floatx4*)((float*)out + ofs)     = vL;
            *(floatx4*)((float*)out + ofs + 4) = vH;
        } else {
            uint4 ou;
            ou.x = ((unsigned int)f2bf(vL.y) << 16) | (unsigned int)f2bf(vL.x);
            ou.y = ((unsigned int)f2bf(vL.w) << 16) | (unsigned int)f2bf(vL.z);
            ou.z = ((unsigned int)f2bf(vH.y) << 16) | (unsigned int)f2bf(vH.x);
            ou.w = ((unsigned int)f2bf(vH.w) << 16) | (unsigned int)f2bf(vH.z);
            *(uint4*)((ushort_t*)out + ofs) = ou;
        }
    }
}

// ---------------------------------------------------------------------------
extern "C" void kernel_launch(void* const* d_in, const int* in_sizes, int n_in,
                              void* d_out, int out_size, void* d_ws, size_t ws_size,
                              hipStream_t stream) {
    const int* nbr    = (const int*)d_in[0];
    const void* verts = d_in[1];
    const void* fm    = d_in[2];
    const void* dirs  = d_in[3];
    const void* Wg    = d_in[4];
    // d_in[5] = b: cancels exactly under train-mode BatchNorm -> unused
    const void* gamma = d_in[6];
    const void* beta  = d_in[7];
    (void)d_ws; (void)ws_size; (void)in_sizes; (void)n_in; (void)out_size;

    hist_kernel<<<dim3(HB + 32), dim3(256), 0, stream>>>(nbr, Wg, verts);
    ygemm_kernel<<<dim3(NPTS / 64), dim3(256), 0, stream>>>(fm, verts);
    finalize_kernel<<<dim3(1), dim3(256), 0, stream>>>(gamma, beta, dirs, verts);
    epi_kernel<<<dim3(NPTS / 4), dim3(256), 0, stream>>>(nbr, verts, d_out);
}

// Round 7
// 138.594 us; speedup vs baseline: 1.0169x; 1.0169x over previous
//
#include <hip/hip_runtime.h>

typedef unsigned short ushort_t;
typedef __attribute__((ext_vector_type(8))) short short8;   // 8 bf16 payload (4 VGPRs)
typedef __attribute__((ext_vector_type(4))) float floatx4;  // MFMA C/D
typedef __attribute__((ext_vector_type(2))) float floatx2;  // v_pk_* f32 pairs

#define NN    32
#define CIN   128
#define COUT  256
#define NPTS  16384            // bs*v = 4*4096
#define NSAMP (NPTS * NN)      // 524288
#define LDA   136              // LDS A-tile stride (+16B pad)
#define HB    128              // histogram partial blocks (32 per batch)

// All scratch in .so-resident device globals. NO atomics anywhere -> every
// buffer is fully overwritten each run -> no zeroing kernel, no cross-run state.
__device__ __align__(16) ushort_t g_wb[COUT * CIN];            // 64 KB: W as bf16
__device__ __align__(16) ushort_t g_y[(size_t)NPTS * COUT];    // 8 MB: Y = fsp * W^T, bf16
__device__ __align__(16) int      g_hp[HB * 4096];             // 2 MB: per-chunk histograms
__device__ __align__(16) float    g_sp[256 * 512];             // 512 KB: per-block BN partials
__device__ __align__(16) float    g_consts[1536];              // scale,shift,d0,s0,s1,s2 per ch

__device__ __forceinline__ float bf2f(ushort_t u) {
    return __uint_as_float(((unsigned int)u) << 16);
}
__device__ __forceinline__ ushort_t f2bf(float f) {
    unsigned int x = __float_as_uint(f);
    return (ushort_t)((x + 0x7FFFu + ((x >> 16) & 1u)) >> 16);  // RNE
}
// Per-wave dtype probe: bf16 verts look plausible as bf16; f32 low halves don't.
__device__ __forceinline__ int probe_f32(const void* verts, int lane) {
    float ax = fabsf(bf2f(((const ushort_t*)verts)[lane]));
    unsigned long long b = __ballot((ax > 1e-5f) && (ax < 32.0f));
    return (__popcll(b) >= 56) ? 0 : 1;
}
__device__ __forceinline__ float bperm_f(int abytes, float v) {
    return __uint_as_float((unsigned)__builtin_amdgcn_ds_bpermute(abytes, __float_as_int(v)));
}
// Packed 2xf32 ops: MI355X's 157.3 TF fp32 REQUIRES VOP3P (v_pk_*); scalar
// v_fma_f32 runs at half rate. hipcc scalarizes ext-vector math, so force it.
__device__ __forceinline__ floatx2 pk_fma(floatx2 a, floatx2 b, floatx2 c) {
    floatx2 d;
    asm("v_pk_fma_f32 %0, %1, %2, %3" : "=v"(d) : "v"(a), "v"(b), "v"(c));
    return d;
}
__device__ __forceinline__ floatx2 pk_mul(floatx2 a, floatx2 b) {
    floatx2 d;
    asm("v_pk_mul_f32 %0, %1, %2" : "=v"(d) : "v"(a), "v"(b));
    return d;
}

// ---------------------------------------------------------------------------
// Kernel 1: atomic-free neighbor histogram partials + W -> bf16.
// ---------------------------------------------------------------------------
__global__ __launch_bounds__(256)
void hist_kernel(const int* __restrict__ nbr,
                 const void* __restrict__ Wg,
                 const void* __restrict__ verts) {
    __shared__ int h[4096];
    const int b   = blockIdx.x;
    const int tid = threadIdx.x;
    if (b < HB) {
        #pragma unroll
        for (int i = 0; i < 16; ++i) h[i * 256 + tid] = 0;
        __syncthreads();
        const int* src = nbr + (size_t)b * 4096;
        #pragma unroll
        for (int i = 0; i < 16; ++i) atomicAdd(&h[src[i * 256 + tid]], 1);  // LDS atomics only
        __syncthreads();
        int* dst = g_hp + (size_t)b * 4096;
        #pragma unroll
        for (int i = 0; i < 16; ++i) dst[i * 256 + tid] = h[i * 256 + tid];
    } else {
        const int f32 = probe_f32(verts, tid & 63);
        int i = (b - HB) * 1024 + tid * 4;
        if (f32) {
            float4 v = ((const float4*)Wg)[i >> 2];
            g_wb[i] = f2bf(v.x); g_wb[i + 1] = f2bf(v.y);
            g_wb[i + 2] = f2bf(v.z); g_wb[i + 3] = f2bf(v.w);
        } else {
            *(uint2*)(g_wb + i) = *(const uint2*)((const ushort_t*)Wg + i);
        }
    }
}

// ---------------------------------------------------------------------------
// Kernel 2: fused fsp-build + Y-GEMM + BN partial stats (no atomics).
// ---------------------------------------------------------------------------
__global__ __launch_bounds__(256, 2)
void ygemm_kernel(const void* __restrict__ fm, const void* __restrict__ verts) {
    __shared__ __align__(16) ushort_t At[64 * LDA];
    __shared__ float multS[64];

    const int tid  = threadIdx.x;
    const int r0   = blockIdx.x * 64;
    const int lane = tid & 63;
    const int f32  = probe_f32(verts, lane);

    if (tid < 64) {   // multiplicity = sum of the batch's 32 histogram partials
        const int* hp = g_hp + (size_t)(r0 >> 12) * 32 * 4096 + (r0 & 4095) + tid;
        int s = 0;
        #pragma unroll
        for (int p2 = 0; p2 < 32; ++p2) s += hp[(size_t)p2 * 4096];
        multS[tid] = (float)s;
    }

    const int rl4 = tid >> 6;
    #pragma unroll 4
    for (int i = 0; i < 16; ++i) {
        const int rl = i * 4 + rl4;
        float f0, f1; ushort_t u0, u1;
        if (f32) {
            const float* src = (const float*)fm + (size_t)(r0 + rl) * 127;
            f0 = src[lane];
            f1 = (lane < 63) ? src[64 + lane] : 0.0f;
            u0 = f2bf(f0); u1 = f2bf(f1);
        } else {
            const ushort_t* src = (const ushort_t*)fm + (size_t)(r0 + rl) * 127;
            u0 = src[lane];
            u1 = (lane < 63) ? src[64 + lane] : (ushort_t)0;
            f0 = bf2f(u0); f1 = bf2f(u1);
        }
        float ss = f0 * f0 + f1 * f1;                 // fdist in fp32 (matches ref)
        #pragma unroll
        for (int d = 1; d < 64; d <<= 1) ss += __shfl_xor(ss, d, 64);
        At[rl * LDA + lane]      = u0;
        At[rl * LDA + 64 + lane] = (lane < 63) ? u1 : f2bf(sqrtf(ss));
    }
    __syncthreads();

    const int w = tid >> 6;              // wave -> channel strip w*64
    const int m = lane & 15;
    const int q = lane >> 4;

    floatx4 acc[4][4];
    #pragma unroll
    for (int rt = 0; rt < 4; ++rt)
        #pragma unroll
        for (int ct = 0; ct < 4; ++ct)
            acc[rt][ct] = (floatx4){0.0f, 0.0f, 0.0f, 0.0f};

    #pragma unroll
    for (int kk = 0; kk < 4; ++kk) {
        const int kof = kk * 32 + q * 8;
        short8 af[4];
        #pragma unroll
        for (int rt = 0; rt < 4; ++rt)
            af[rt] = *(const short8*)&At[(rt * 16 + m) * LDA + kof];
        short8 bfr[4];
        #pragma unroll
        for (int ct = 0; ct < 4; ++ct) {
            int ch = w * 64 + ct * 16 + m;
            bfr[ct] = *(const short8*)(g_wb + ch * CIN + kof);  // B[k][n]=W[n][k]
        }
        #pragma unroll
        for (int rt = 0; rt < 4; ++rt)
            #pragma unroll
            for (int ct = 0; ct < 4; ++ct)
                acc[rt][ct] = __builtin_amdgcn_mfma_f32_16x16x32_bf16(
                    af[rt], bfr[ct], acc[rt][ct], 0, 0, 0);
    }

    #pragma unroll
    for (int ct = 0; ct < 4; ++ct) {
        const int ch = w * 64 + ct * 16 + m;
        float s = 0.0f, ss = 0.0f;
        #pragma unroll
        for (int rt = 0; rt < 4; ++rt)
            #pragma unroll
            for (int j = 0; j < 4; ++j) {
                int rloc = rt * 16 + q * 4 + j;       // C/D: row=(lane>>4)*4+reg
                ushort_t yb = f2bf(acc[rt][ct][j]);
                g_y[(size_t)(r0 + rloc) * COUT + ch] = yb;
                float yv = bf2f(yb);                  // same value epi will read
                float wm = multS[rloc];
                s  += wm * yv;
                ss += wm * yv * yv;
            }
        s  += __shfl_xor(s, 16, 64);  s  += __shfl_xor(s, 32, 64);
        ss += __shfl_xor(ss, 16, 64); ss += __shfl_xor(ss, 32, 64);
        if (q == 0) {                                 // plain stores, no atomics
            g_sp[(size_t)blockIdx.x * 512 + ch]       = s;
            g_sp[(size_t)blockIdx.x * 512 + 256 + ch] = ss;
        }
    }
}

// ---------------------------------------------------------------------------
// Kernel 3: reduce the 256 BN partials + per-channel constants.
// 1024 threads: 4 readers per channel (4x the read parallelism of the old
// 256-thread version; this single block's 512KB serial read was ~3-5us),
// LDS tree-combine, then t<256 writes the folded constants.
// ---------------------------------------------------------------------------
__global__ __launch_bounds__(1024)
void finalize_kernel(const void* __restrict__ gamma,
                     const void* __restrict__ beta,
                     const void* __restrict__ dirs,
                     const void* __restrict__ verts) {
    __shared__ float redS[1024], redQ[1024];
    const int t    = threadIdx.x;
    const int c    = t & 255;
    const int part = t >> 8;                          // 0..3: 64 partials each
    const int f32  = probe_f32(verts, t & 63);

    float s = 0.0f, ss = 0.0f;
    #pragma unroll 8
    for (int i = 0; i < 64; ++i) {
        const int p2 = part * 64 + i;
        s  += g_sp[(size_t)p2 * 512 + c];
        ss += g_sp[(size_t)p2 * 512 + 256 + c];
    }
    redS[t] = s; redQ[t] = ss;
    __syncthreads();
    if (t < 256) {
        s  = redS[t] + redS[t + 256] + redS[t + 512] + redS[t + 768];
        ss = redQ[t] + redQ[t + 256] + redQ[t + 512] + redQ[t + 768];
        const float invN = 1.0f / (float)NSAMP;
        float mean = s * invN;
        float var  = fmaxf(ss * invN - mean * mean, 0.0f);  // biased
        float inv  = 1.0f / sqrtf(var + 1e-5f);
        float ga, be, d0, d1, d2, d3;
        if (f32) {
            ga = ((const float*)gamma)[c]; be = ((const float*)beta)[c];
            const float* dd = (const float*)dirs;
            d0 = dd[c]; d1 = dd[256 + c]; d2 = dd[512 + c]; d3 = dd[768 + c];
        } else {
            ga = bf2f(((const ushort_t*)gamma)[c]); be = bf2f(((const ushort_t*)beta)[c]);
            const ushort_t* dd = (const ushort_t*)dirs;
            d0 = bf2f(dd[c]); d1 = bf2f(dd[256 + c]);
            d2 = bf2f(dd[512 + c]); d3 = bf2f(dd[768 + c]);
        }
        float scale = ga * inv;
        g_consts[c]        = scale;
        g_consts[256 + c]  = be - mean * scale;       // bias b cancels in train-BN
        g_consts[512 + c]  = d0;                      // directions[0]
        g_consts[768 + c]  = d1 - d0;                 // sup_w rows
        g_consts[1024 + c] = d2 - d0;
        g_consts[1280 + c] = d3 - d0;
    }
}

// ---------------------------------------------------------------------------
// Kernel 4: epilogue, same structure as round 6 (wave/point, half-wave/sample,
// 8 ch/lane, dwordx4 pair loads, ds_bpermute broadcasts, barrier-free) but the
// per-channel math now runs on the PACKED fp32 pipe: th chain / zn-FMA / mul
// as v_pk_fma_f32 / v_pk_mul_f32 (2 ch per inst). Dominant VALU stream per
// pair drops ~64 -> ~42 insts. Packed broadcast weights built at prefetch
// time (off the critical path). clamp/max stay scalar (no v_pk_max_f32).
// XCD-chunked: blocks bid&7==k cover p in [k*2048,(k+1)*2048).
// ---------------------------------------------------------------------------
__global__ __launch_bounds__(256, 4)
void epi_kernel(const int* __restrict__ nbr,
                const void* __restrict__ verts,
                void* __restrict__ out) {
    const int tid  = threadIdx.x;
    const int lane = tid & 63;
    const int bid  = blockIdx.x;
    const int p0   = (((bid & 7) << 9) | (bid >> 3)) << 2;   // XCD-chunked, 4 pts
    const int p    = p0 + (tid >> 6);                        // wave -> point
    const int f32  = probe_f32(verts, lane);
    const int j    = lane & 31;                              // owned neighbor

    // --- setup: per-lane direction weight + row, held in VGPRs (no LDS).
    int   gv;                                                // gathered row
    float wx, wy, wz;
    {
        gv = ((p >> 12) << 12) + nbr[(size_t)p * NN + j];
        float sx, sy, sz, nx, ny, nz;
        if (f32) {
            const float* vv = (const float*)verts;
            sx = vv[p * 3]; sy = vv[p * 3 + 1]; sz = vv[p * 3 + 2];
            nx = vv[gv * 3]; ny = vv[gv * 3 + 1]; nz = vv[gv * 3 + 2];
        } else {
            const ushort_t* vv = (const ushort_t*)verts;
            sx = bf2f(vv[p * 3]); sy = bf2f(vv[p * 3 + 1]); sz = bf2f(vv[p * 3 + 2]);
            nx = bf2f(vv[gv * 3]); ny = bf2f(vv[gv * 3 + 1]); nz = bf2f(vv[gv * 3 + 2]);
        }
        float dx = nx - sx, dy = ny - sy, dz = nz - sz;
        float nrm = sqrtf(dx * dx + dy * dy + dz * dz);
        float inv = 1.0f / fmaxf(nrm, 1e-12f);               // F.normalize eps
        wx = (dx * inv + 1.0f) * 0.5f;
        wy = (dy * inv + 1.0f) * 0.5f;
        wz = (dz * inv + 1.0f) * 0.5f;
    }

    const int hsel = (lane >> 5) << 2;        // bpermute byte addr: which half
    const int cofs = (lane & 31) << 4;        // lane's 16B (8 ch) within a row
    const int c8   = (lane & 31) * 8;         // 8 channels per lane

    const floatx2 zero2 = {0.0f, 0.0f};
    floatx2 sc2[4], sh2[4], d02[4], s02[4], s12[4], s22[4];
    #pragma unroll
    for (int c = 0; c < 4; ++c) {
        sc2[c] = *(const floatx2*)&g_consts[c8 + 2 * c];
        sh2[c] = *(const floatx2*)&g_consts[256 + c8 + 2 * c];
        d02[c] = *(const floatx2*)&g_consts[512 + c8 + 2 * c];
        s02[c] = *(const floatx2*)&g_consts[768 + c8 + 2 * c];
        s12[c] = *(const floatx2*)&g_consts[1024 + c8 + 2 * c];
        s22[c] = *(const floatx2*)&g_consts[1280 + c8 + 2 * c];
    }

    const char* gyb = (const char*)g_y;
    floatx2 acc2[4] = {zero2, zero2, zero2, zero2};          // 8 ch running max
    uint4 u[4]; floatx2 bxp[4], byp[4], bzp[4];              // 4-pair pipeline

    #pragma unroll
    for (int k = 0; k < 4; ++k) {                            // prologue: pairs 0..3
        const int av = k * 8 + hsel;
        int rw = __builtin_amdgcn_ds_bpermute(av, gv);       // DS-pipe broadcasts
        float t0 = bperm_f(av, wx), t1 = bperm_f(av, wy), t2 = bperm_f(av, wz);
        bxp[k] = (floatx2){t0, t0};                          // packed duplicates
        byp[k] = (floatx2){t1, t1};
        bzp[k] = (floatx2){t2, t2};
        u[k] = *(const uint4*)(gyb + (((unsigned)rw << 9) + (unsigned)cofs));
    }
    #pragma unroll
    for (int g = 0; g < 4; ++g) {
        #pragma unroll
        for (int k = 0; k < 4; ++k) {
            const uint4 uk = u[k];                           // waits this load only
            const floatx2 wxk = bxp[k], wyk = byp[k], wzk = bzp[k];
            if (g < 3) {                                     // prefetch pair +4
                const int av = (g * 4 + k + 4) * 8 + hsel;
                int rw = __builtin_amdgcn_ds_bpermute(av, gv);
                float t0 = bperm_f(av, wx), t1 = bperm_f(av, wy), t2 = bperm_f(av, wz);
                bxp[k] = (floatx2){t0, t0};
                byp[k] = (floatx2){t1, t1};
                bzp[k] = (floatx2){t2, t2};
                u[k] = *(const uint4*)(gyb + (((unsigned)rw << 9) + (unsigned)cofs));
            }
            const unsigned uc[4] = {uk.x, uk.y, uk.z, uk.w};
            #pragma unroll
            for (int c = 0; c < 4; ++c) {                    // 2 ch per chunk
                floatx2 y;
                y.x = __uint_as_float(uc[c] << 16);
                y.y = __uint_as_float(uc[c] & 0xFFFF0000u);
                floatx2 th = pk_fma(wzk, s22[c],
                             pk_fma(wyk, s12[c],
                             pk_fma(wxk, s02[c], d02[c])));  // 3 pk-FMA
                th = __builtin_elementwise_max(th, zero2);   // relu(theta)
                floatx2 zt = pk_mul(pk_fma(y, sc2[c], sh2[c]), th);
                acc2[c] = __builtin_elementwise_max(acc2[c], zt);
            }
        }
    }

    // merge even-sample half with odd-sample half (same channels, lane^32)
    #pragma unroll
    for (int c = 0; c < 4; ++c) {
        acc2[c].x = fmaxf(acc2[c].x, __shfl_xor(acc2[c].x, 32, 64));
        acc2[c].y = fmaxf(acc2[c].y, __shfl_xor(acc2[c].y, 32, 64));
    }

    if (lane < 32) {
        size_t ofs = (size_t)p * COUT + c8;
        if (f32) {
            floatx4 oL = {acc2[0].x, acc2[0].y, acc2[1].x, acc2[1].y};
            floatx4 oH = {acc2[2].x, acc2[2].y, acc2[3].x, acc2[3].y};
            *(floatx4*)((float*)out + ofs)     = oL;
            *(floatx4*)((float*)out + ofs + 4) = oH;
        } else {
            uint4 ou;
            ou.x = ((unsigned int)f2bf(acc2[0].y) << 16) | (unsigned int)f2bf(acc2[0].x);
            ou.y = ((unsigned int)f2bf(acc2[1].y) << 16) | (unsigned int)f2bf(acc2[1].x);
            ou.z = ((unsigned int)f2bf(acc2[2].y) << 16) | (unsigned int)f2bf(acc2[2].x);
            ou.w = ((unsigned int)f2bf(acc2[3].y) << 16) | (unsigned int)f2bf(acc2[3].x);
            *(uint4*)((ushort_t*)out + ofs) = ou;
        }
    }
}

// ---------------------------------------------------------------------------
extern "C" void kernel_launch(void* const* d_in, const int* in_sizes, int n_in,
                              void* d_out, int out_size, void* d_ws, size_t ws_size,
                              hipStream_t stream) {
    const int* nbr    = (const int*)d_in[0];
    const void* verts = d_in[1];
    const void* fm    = d_in[2];
    const void* dirs  = d_in[3];
    const void* Wg    = d_in[4];
    // d_in[5] = b: cancels exactly under train-mode BatchNorm -> unused
    const void* gamma = d_in[6];
    const void* beta  = d_in[7];
    (void)d_ws; (void)ws_size; (void)in_sizes; (void)n_in; (void)out_size;

    hist_kernel<<<dim3(HB + 32), dim3(256), 0, stream>>>(nbr, Wg, verts);
    ygemm_kernel<<<dim3(NPTS / 64), dim3(256), 0, stream>>>(fm, verts);
    finalize_kernel<<<dim3(1), dim3(1024), 0, stream>>>(gamma, beta, dirs, verts);
    epi_kernel<<<dim3(NPTS / 4), dim3(256), 0, stream>>>(nbr, verts, d_out);
}